// Round 1
// baseline (546.727 us; speedup 1.0000x reference)
//
#include <hip/hip_runtime.h>
#include <stdint.h>

#define NPIX 6084      // 78*78 pixels / patches
#define NPAD 6144      // padded to 48*128
#define KDIM 2304      // 256*3*3
#define KB   (KDIM*2)  // row bytes in bf16 = 4608

typedef __attribute__((ext_vector_type(8))) short s16x8;
typedef __attribute__((ext_vector_type(4))) float f32x4;

__device__ __forceinline__ short f2bf(float f) {
  unsigned u = __builtin_bit_cast(unsigned, f);
  u += 0x7FFFu + ((u >> 16) & 1u);
  return (short)(u >> 16);
}
__device__ __forceinline__ float bf2f(short s) {
  unsigned u = ((unsigned)(unsigned short)s) << 16;
  return __builtin_bit_cast(float, u);
}

#define GL16(g, l)                                                            \
  __builtin_amdgcn_global_load_lds(                                           \
      (__attribute__((address_space(1))) unsigned int*)(g),                   \
      (__attribute__((address_space(3))) unsigned int*)(l), 16, 0, 0)

// ---------------- prep: cast patches f32 -> bf16, pad rows to 6144 ----------
__global__ __launch_bounds__(256) void k_prep_pat(const float* __restrict__ pat,
                                                  short* __restrict__ out) {
  int i = blockIdx.x * 256 + threadIdx.x;  // one 8-elem chunk
  int e0 = i * 8;
  int row = e0 / KDIM;
  s16x8 v;
  if (row < NPIX) {
    const float* s = pat + e0;
#pragma unroll
    for (int j = 0; j < 8; ++j) v[j] = f2bf(s[j]);
  } else {
#pragma unroll
    for (int j = 0; j < 8; ++j) v[j] = 0;
  }
  *(s16x8*)(out + e0) = v;
}

// ---------------- prep: im2col of x into bf16 [6144][2304] ------------------
__global__ __launch_bounds__(256) void k_prep_xcol(const float* __restrict__ x,
                                                   short* __restrict__ out) {
  int i = blockIdx.x * 256 + threadIdx.x;
  int e0 = i * 8;
  int m = e0 / KDIM;
  int k0 = e0 - m * KDIM;
  s16x8 v;
  if (m < NPIX) {
    int p = m / 78, q = m - p * 78;
#pragma unroll
    for (int j = 0; j < 8; ++j) {
      int k = k0 + j;
      int c = k / 9;
      int r = k - c * 9;
      int dy = r / 3, dx = r - dy * 3;
      v[j] = f2bf(x[c * 6400 + (p + dy) * 80 + (q + dx)]);
    }
  } else {
#pragma unroll
    for (int j = 0; j < 8; ++j) v[j] = 0;
  }
  *(s16x8*)(out + e0) = v;
}

// ---------------- GEMM: sim[pixel][patch] = A(xcol) . B(patches)^T ----------
// m97 structure: 128x128 tile, BK=32, 4 waves (2x2), 4x4 16x16x32 bf16 frags,
// global_load_lds width-16 staging, bf16 output.
__global__ __launch_bounds__(256) void k_gemm(const short* __restrict__ A,
                                              const short* __restrict__ B,
                                              short* __restrict__ C) {
  __shared__ short As[128 * 32];
  __shared__ short Bs[128 * 32];
  const int tid = threadIdx.x;
  const int w = tid >> 6, lane = tid & 63;
  const int wr = w >> 1, wc = w & 1;
  const int tm = blockIdx.y, tn = blockIdx.x;
  const char* Ab = (const char*)A + (size_t)tm * 128 * KB;
  const char* Bb = (const char*)B + (size_t)tn * 128 * KB;
  const int r0 = lane >> 2;          // row within 16-row chunk
  const int kbyte = (lane & 3) * 16; // byte offset within 64-byte k-row
  f32x4 acc[4][4] = {};

  const short* ap = &As[(wr * 64 + (lane & 15)) * 32 + (lane >> 4) * 8];
  const short* bp = &Bs[(wc * 64 + (lane & 15)) * 32 + (lane >> 4) * 8];

  for (int kk = 0; kk < KDIM; kk += 32) {
#pragma unroll
    for (int o = 0; o < 2; ++o) {
      int ch = o * 4 + w;            // 8 chunks of 1 KiB
      int r = ch * 16 + r0;
      GL16(Ab + (size_t)r * KB + kk * 2 + kbyte, &As[ch * 512]);
      GL16(Bb + (size_t)r * KB + kk * 2 + kbyte, &Bs[ch * 512]);
    }
    asm volatile("s_waitcnt vmcnt(0)" ::: "memory");
    __syncthreads();
    s16x8 a[4], b[4];
#pragma unroll
    for (int i = 0; i < 4; ++i) a[i] = *(const s16x8*)(ap + i * 512);
#pragma unroll
    for (int i = 0; i < 4; ++i) b[i] = *(const s16x8*)(bp + i * 512);
#pragma unroll
    for (int mi = 0; mi < 4; ++mi)
#pragma unroll
      for (int ni = 0; ni < 4; ++ni)
        acc[mi][ni] = __builtin_amdgcn_mfma_f32_16x16x32_bf16(
            a[mi], b[ni], acc[mi][ni], 0, 0, 0);
    __syncthreads();
  }

  const int rowb = tm * 128 + wr * 64 + (lane >> 4) * 4;
  const int colb = tn * 128 + wc * 64 + (lane & 15);
#pragma unroll
  for (int mi = 0; mi < 4; ++mi)
#pragma unroll
    for (int ni = 0; ni < 4; ++ni)
#pragma unroll
      for (int j = 0; j < 4; ++j)
        C[(size_t)(rowb + mi * 16 + j) * NPAD + colb + ni * 16] =
            f2bf(acc[mi][ni][j]);
}

// ------------- argmax per pixel row + f64 rescore of near-ties --------------
__global__ __launch_bounds__(256) void k_argmax(const short* __restrict__ sim,
                                                const float* __restrict__ x,
                                                const float* __restrict__ pat,
                                                int* __restrict__ amax) {
  __shared__ int cand[4][32];
  __shared__ int ccnt[4];
  const int tid = threadIdx.x, w = tid >> 6, lane = tid & 63;
  const int pix = blockIdx.x * 4 + w;  // grid is exactly 6084/4
  const short* row = sim + (size_t)pix * NPAD;

  float best = -1e30f;
  int bidx = 0;
  for (int it = 0; it < 12; ++it) {
    int k0 = (it * 64 + lane) * 8;
    if (k0 < NPIX) {
      s16x8 v = *(const s16x8*)(row + k0);
#pragma unroll
      for (int j = 0; j < 8; ++j) {
        int k = k0 + j;
        float f = bf2f(v[j]);
        if (k < NPIX && (f > best || (f == best && k < bidx))) {
          best = f; bidx = k;
        }
      }
    }
  }
  for (int off = 32; off; off >>= 1) {
    float ov = __shfl_down(best, off);
    int oi = __shfl_down(bidx, off);
    if (ov > best || (ov == best && oi < bidx)) { best = ov; bidx = oi; }
  }
  float maxv = __shfl(best, 0);

  if (lane == 0) ccnt[w] = 0;
  __syncthreads();

  const float thr = maxv - 4.0f;  // covers bf16 matmul + storage error
  for (int it = 0; it < 12; ++it) {
    int k0 = (it * 64 + lane) * 8;
    if (k0 < NPIX) {
      s16x8 v = *(const s16x8*)(row + k0);
#pragma unroll
      for (int j = 0; j < 8; ++j) {
        int k = k0 + j;
        float f = bf2f(v[j]);
        if (k < NPIX && f >= thr) {
          int pos = atomicAdd(&ccnt[w], 1);
          if (pos < 32) cand[w][pos] = k;
        }
      }
    }
  }
  __syncthreads();

  int n = ccnt[w] < 32 ? ccnt[w] : 32;
  const int p = pix / 78, q = pix - (pix / 78) * 78;
  double bests = -1e300;
  int bestk = 0;
  for (int ci = 0; ci < n; ++ci) {
    int k = cand[w][ci];
    double s = 0.0;
    for (int cc = lane; cc < 256; cc += 64) {
      const float* xb = x + cc * 6400 + p * 80 + q;
      const float* pb = pat + (size_t)k * KDIM + cc * 9;
#pragma unroll
      for (int dy = 0; dy < 3; ++dy)
#pragma unroll
        for (int dx = 0; dx < 3; ++dx)
          s += (double)xb[dy * 80 + dx] * (double)pb[dy * 3 + dx];
    }
    for (int off = 32; off; off >>= 1) s += __shfl_down(s, off);
    if (lane == 0 && (s > bests || (s == bests && k < bestk))) {
      bests = s; bestk = k;
    }
  }
  if (lane == 0) amax[pix] = bestk;
}

// ------------- output: gather <=9 overlapping patch values, divide ----------
__global__ __launch_bounds__(256) void k_out(const float* __restrict__ pat,
                                             const int* __restrict__ amax,
                                             float* __restrict__ out) {
  int i = blockIdx.x * 256 + threadIdx.x;  // 256*80*80 exact
  int xx = i % 80;
  int rest = i / 80;
  int yy = rest % 80;
  int c = rest / 80;
  int p0 = yy - 2 > 0 ? yy - 2 : 0, p1 = yy < 77 ? yy : 77;
  int q0 = xx - 2 > 0 ? xx - 2 : 0, q1 = xx < 77 ? xx : 77;
  float s = 0.f;
  for (int p = p0; p <= p1; ++p)
    for (int q = q0; q <= q1; ++q) {
      int k = amax[p * 78 + q];
      s += pat[(size_t)k * KDIM + c * 9 + (yy - p) * 3 + (xx - q)];
    }
  int cnt = (p1 - p0 + 1) * (q1 - q0 + 1);
  out[i] = s / (float)cnt;
}

extern "C" void kernel_launch(void* const* d_in, const int* in_sizes, int n_in,
                              void* d_out, int out_size, void* d_ws,
                              size_t ws_size, hipStream_t stream) {
  const float* x = (const float*)d_in[0];    // (1,256,80,80) f32
  const float* pat = (const float*)d_in[1];  // (6084,256,3,3) f32
  float* out = (float*)d_out;                // (1,256,80,80) f32
  char* ws = (char*)d_ws;

  short* patB = (short*)ws;                          // 28,311,552 B
  short* xcol = (short*)(ws + 28311552);             // 28,311,552 B
  short* sim  = (short*)(ws + 2 * 28311552);         // 75,497,472 B
  int*   amax = (int*)(ws + 2 * 28311552 + 75497472);// 24,336 B

  k_prep_pat<<<6912, 256, 0, stream>>>(pat, patB);
  k_prep_xcol<<<6912, 256, 0, stream>>>(x, xcol);
  k_gemm<<<dim3(48, 48), 256, 0, stream>>>(xcol, patB, sim);
  k_argmax<<<1521, 256, 0, stream>>>(sim, x, pat, amax);
  k_out<<<6400, 256, 0, stream>>>(pat, amax, out);
}